// Round 1
// baseline (2052.804 us; speedup 1.0000x reference)
//
#include <hip/hip_runtime.h>
#include <cstdint>

#define N_NODES 20000
#define N_EDGES 320000
#define ALPHA 0.2f
#define GAT_EPS 1e-16f

__device__ __forceinline__ float elu1(float x) { return x > 0.f ? x : __expf(x) - 1.f; }

// ---------------- CSR build ----------------
__global__ void hist_kernel(const int* __restrict__ dst, int* __restrict__ counts, int E) {
    int e = blockIdx.x * blockDim.x + threadIdx.x;
    if (e < E) atomicAdd(&counts[dst[e]], 1);
}

__global__ void scan_kernel(const int* __restrict__ counts, int* __restrict__ rowptr,
                            int* __restrict__ cursor, int N) {
    __shared__ int sh[1024];
    int tid = threadIdx.x;
    int offset = 0;
    for (int base = 0; base < N; base += 1024) {
        int i = base + tid;
        int v = (i < N) ? counts[i] : 0;
        sh[tid] = v;
        __syncthreads();
        for (int d = 1; d < 1024; d <<= 1) {
            int t = (tid >= d) ? sh[tid - d] : 0;
            __syncthreads();
            sh[tid] += t;
            __syncthreads();
        }
        int excl = sh[tid] - v;
        if (i < N) { rowptr[i] = offset + excl; cursor[i] = offset + excl; }
        int tot = sh[1023];
        __syncthreads();
        offset += tot;
    }
    if (tid == 0) rowptr[N] = offset;
}

__global__ void scatter_kernel(const int* __restrict__ src, const int* __restrict__ dst,
                               int* __restrict__ cursor, int* __restrict__ esrc, int E) {
    int e = blockIdx.x * blockDim.x + threadIdx.x;
    if (e < E) {
        int p = atomicAdd(&cursor[dst[e]], 1);
        esrc[p] = src[e];
    }
}

// ---------------- fp32 GEMM: C[M,Ntot] = A[M,K] @ Wheads ----------------
// B layout: per head h (Fout cols each): B[h*K*Fout + k*Fout + f], col c -> h=c/Fout, f=c%Fout
#define BM 128
#define BN 128
#define BK 16
__global__ __launch_bounds__(256) void gemm_f32(const float* __restrict__ A,
                                                const float* __restrict__ B,
                                                float* __restrict__ C,
                                                int M, int K, int Ntot, int Fout) {
    __shared__ float As[BK][BM + 4];
    __shared__ float Bs[BK][BN + 4];
    int tid = threadIdx.x;
    int row0 = blockIdx.y * BM, col0 = blockIdx.x * BN;
    int tr = tid >> 4, tc = tid & 15;
    int ar = tid >> 1, ac = (tid & 1) * 8;
    int br = tid >> 4, bc = (tid & 15) * 8;
    float acc[8][8] = {};
    bool vecA = ((K & 3) == 0);
    for (int k0 = 0; k0 < K; k0 += BK) {
        int arow = row0 + ar;
        float av[8] = {0, 0, 0, 0, 0, 0, 0, 0};
        if (arow < M) {
            const float* Ap = A + (size_t)arow * K + k0 + ac;
            if (vecA && k0 + BK <= K) {
                float4 v0 = *(const float4*)Ap;
                float4 v1 = *(const float4*)(Ap + 4);
                av[0] = v0.x; av[1] = v0.y; av[2] = v0.z; av[3] = v0.w;
                av[4] = v1.x; av[5] = v1.y; av[6] = v1.z; av[7] = v1.w;
            } else {
#pragma unroll
                for (int i = 0; i < 8; i++)
                    if (k0 + ac + i < K) av[i] = Ap[i];
            }
        }
#pragma unroll
        for (int i = 0; i < 8; i++) As[ac + i][ar] = av[i];
        int kb = k0 + br;
#pragma unroll
        for (int j = 0; j < 8; j++) {
            int c = col0 + bc + j;
            float v = 0.f;
            if (kb < K && c < Ntot) {
                int h = c / Fout;
                int f = c - h * Fout;
                v = B[(size_t)h * K * Fout + (size_t)kb * Fout + f];
            }
            Bs[br][bc + j] = v;
        }
        __syncthreads();
#pragma unroll
        for (int kk = 0; kk < BK; kk++) {
            float a8[8], b8[8];
#pragma unroll
            for (int i = 0; i < 8; i++) a8[i] = As[kk][tr * 8 + i];
#pragma unroll
            for (int j = 0; j < 8; j++) b8[j] = Bs[kk][tc * 8 + j];
#pragma unroll
            for (int i = 0; i < 8; i++)
#pragma unroll
                for (int j = 0; j < 8; j++) acc[i][j] += a8[i] * b8[j];
        }
        __syncthreads();
    }
#pragma unroll
    for (int i = 0; i < 8; i++) {
        int r = row0 + tr * 8 + i;
        if (r >= M) continue;
#pragma unroll
        for (int j = 0; j < 8; j++) {
            int c = col0 + tc * 8 + j;
            if (c < Ntot) C[(size_t)r * Ntot + c] = acc[i][j];
        }
    }
}

// ---------------- attention scores: s_src/s_dst per (node, head) ----------------
__global__ void scores_kernel(const float* __restrict__ Wh, const float* __restrict__ a,
                              float* __restrict__ ssrc, float* __restrict__ sdst,
                              int N, int H, int Fout, int Ntot) {
    int n = blockIdx.x;
    int h = threadIdx.x >> 6;
    int lane = threadIdx.x & 63;
    if (h >= H) return;
    const float* row = Wh + (size_t)n * Ntot + h * Fout;
    const float* ah = a + (size_t)h * 2 * Fout;
    float s0 = 0.f, s1 = 0.f;
    for (int f = lane; f < Fout; f += 64) {
        float w = row[f];
        s0 += w * ah[f];
        s1 += w * ah[Fout + f];
    }
#pragma unroll
    for (int off = 32; off; off >>= 1) {
        s0 += __shfl_down(s0, off);
        s1 += __shfl_down(s1, off);
    }
    if (lane == 0) {
        ssrc[(size_t)h * N + n] = s0;
        sdst[(size_t)h * N + n] = s1;
    }
}

// ---------------- segment softmax + aggregate, Fout=256 layers ----------------
// out = elu(elu(h) + skip)   (skip==nullptr -> 0; matches per-head elu then post-concat elu)
__global__ __launch_bounds__(64) void agg256_kernel(const float* __restrict__ Wh,
                                                    const int* __restrict__ rowptr,
                                                    const int* __restrict__ esrc,
                                                    const float* __restrict__ ssrc,
                                                    const float* __restrict__ sdst,
                                                    float* __restrict__ out,
                                                    const float* __restrict__ skip, int N) {
    int n = blockIdx.x, h = blockIdx.y, lane = threadIdx.x;
    int start = rowptr[n], end = rowptr[n + 1];
    const float* ss = ssrc + (size_t)h * N;
    float sd = sdst[(size_t)h * N + n];
    float m = -INFINITY;
    for (int e = start + lane; e < end; e += 64) {
        float sc = ss[esrc[e]] + sd;
        sc = sc > 0.f ? sc : ALPHA * sc;
        m = fmaxf(m, sc);
    }
#pragma unroll
    for (int off = 32; off; off >>= 1) m = fmaxf(m, __shfl_down(m, off));
    m = __shfl(m, 0);

    float4 acc = {0.f, 0.f, 0.f, 0.f};
    float psum = 0.f;
    const float* base = Wh + (size_t)h * 256 + lane * 4;
    for (int e = start; e < end; e++) {
        int s = esrc[e];
        float sc = ss[s] + sd;
        sc = sc > 0.f ? sc : ALPHA * sc;
        float p = __expf(sc - m);
        psum += p;
        const float4 w = *(const float4*)(base + (size_t)s * 1024);
        acc.x += p * w.x; acc.y += p * w.y; acc.z += p * w.z; acc.w += p * w.w;
    }
    float inv = 1.f / (psum + GAT_EPS);
    size_t o = (size_t)n * 1024 + h * 256 + lane * 4;
    float sk0 = 0.f, sk1 = 0.f, sk2 = 0.f, sk3 = 0.f;
    if (skip) { sk0 = skip[o]; sk1 = skip[o + 1]; sk2 = skip[o + 2]; sk3 = skip[o + 3]; }
    float4 r;
    r.x = elu1(elu1(acc.x * inv) + sk0);
    r.y = elu1(elu1(acc.y * inv) + sk1);
    r.z = elu1(elu1(acc.z * inv) + sk2);
    r.w = elu1(elu1(acc.w * inv) + sk3);
    *(float4*)(out + o) = r;
}

// ---------------- layer 3: Fout=121, accumulate heads into out, final mean+sigmoid ----------------
__global__ __launch_bounds__(64) void agg121_kernel(const float* __restrict__ Wh,
                                                    const int* __restrict__ rowptr,
                                                    const int* __restrict__ esrc,
                                                    const float* __restrict__ ssrc,
                                                    const float* __restrict__ sdst,
                                                    float* __restrict__ out, int head, int mode) {
    int n = blockIdx.x, lane = threadIdx.x;
    int start = rowptr[n], end = rowptr[n + 1];
    const float* ss = ssrc + (size_t)head * N_NODES;
    float sd = sdst[(size_t)head * N_NODES + n];
    float m = -INFINITY;
    for (int e = start + lane; e < end; e += 64) {
        float sc = ss[esrc[e]] + sd;
        sc = sc > 0.f ? sc : ALPHA * sc;
        m = fmaxf(m, sc);
    }
#pragma unroll
    for (int off = 32; off; off >>= 1) m = fmaxf(m, __shfl_down(m, off));
    m = __shfl(m, 0);

    float acc0 = 0.f, acc1 = 0.f, psum = 0.f;
    const float* base = Wh + (size_t)head * 121;
    for (int e = start; e < end; e++) {
        int s = esrc[e];
        float sc = ss[s] + sd;
        sc = sc > 0.f ? sc : ALPHA * sc;
        float p = __expf(sc - m);
        psum += p;
        const float* row = base + (size_t)s * 726;
        acc0 += p * row[lane];
        if (lane < 57) acc1 += p * row[64 + lane];
    }
    float inv = 1.f / (psum + GAT_EPS);
    float v0 = acc0 * inv, v1 = acc1 * inv;
    float* o = out + (size_t)n * 121;
    if (mode == 0) {
        o[lane] = v0;
        if (lane < 57) o[64 + lane] = v1;
    } else if (mode == 1) {
        o[lane] += v0;
        if (lane < 57) o[64 + lane] += v1;
    } else {
        float x0 = (o[lane] + v0) * (1.f / 6.f);
        o[lane] = 1.f / (1.f + __expf(-x0));
        if (lane < 57) {
            float x1 = (o[64 + lane] + v1) * (1.f / 6.f);
            o[64 + lane] = 1.f / (1.f + __expf(-x1));
        }
    }
}

extern "C" void kernel_launch(void* const* d_in, const int* in_sizes, int n_in,
                              void* d_out, int out_size, void* d_ws, size_t ws_size,
                              hipStream_t stream) {
    const float* x  = (const float*)d_in[0];
    const int*   ei = (const int*)d_in[1];
    const float* W1 = (const float*)d_in[2];
    const float* a1 = (const float*)d_in[3];
    const float* W2 = (const float*)d_in[4];
    const float* a2 = (const float*)d_in[5];
    const float* W3 = (const float*)d_in[6];
    const float* a3 = (const float*)d_in[7];
    float* out = (float*)d_out;
    const int N = N_NODES, E = N_EDGES;
    const int* src = ei;
    const int* dst = ei + E;

    char* ws = (char*)d_ws;
    size_t off = 0;
    auto alloc = [&](size_t b) { size_t o = off; off += (b + 255) & ~(size_t)255; return o; };
    float* X      = (float*)(ws + alloc((size_t)N * 1024 * 4)); // x1 then x2 (in-place)
    float* WH     = (float*)(ws + alloc((size_t)N * 1024 * 4)); // per-layer Wh
    float* SS     = (float*)(ws + alloc((size_t)6 * N * 4));
    float* SD     = (float*)(ws + alloc((size_t)6 * N * 4));
    int*   rowptr = (int*)(ws + alloc((size_t)(N + 1) * 4));
    int*   cursor = (int*)(ws + alloc((size_t)N * 4));
    int*   counts = (int*)(ws + alloc((size_t)N * 4));
    int*   esrc   = (int*)(ws + alloc((size_t)E * 4));

    // CSR by dst
    hipMemsetAsync(counts, 0, (size_t)N * 4, stream);
    hist_kernel<<<(E + 255) / 256, 256, 0, stream>>>(dst, counts, E);
    scan_kernel<<<1, 1024, 0, stream>>>(counts, rowptr, cursor, N);
    scatter_kernel<<<(E + 255) / 256, 256, 0, stream>>>(src, dst, cursor, esrc, E);

    // ---- layer 1: 50 -> 4x256 concat ----
    gemm_f32<<<dim3(8, (N + BM - 1) / BM), 256, 0, stream>>>(x, W1, WH, N, 50, 1024, 256);
    scores_kernel<<<N, 256, 0, stream>>>(WH, a1, SS, SD, N, 4, 256, 1024);
    agg256_kernel<<<dim3(N, 4), 64, 0, stream>>>(WH, rowptr, esrc, SS, SD, X, nullptr, N);

    // ---- layer 2: 1024 -> 4x256 concat + skip ----
    gemm_f32<<<dim3(8, (N + BM - 1) / BM), 256, 0, stream>>>(X, W2, WH, N, 1024, 1024, 256);
    scores_kernel<<<N, 256, 0, stream>>>(WH, a2, SS, SD, N, 4, 256, 1024);
    agg256_kernel<<<dim3(N, 4), 64, 0, stream>>>(WH, rowptr, esrc, SS, SD, X, X, N);

    // ---- layer 3: 1024 -> 6x121, mean over heads, sigmoid ----
    gemm_f32<<<dim3(6, (N + BM - 1) / BM), 256, 0, stream>>>(X, W3, WH, N, 1024, 726, 121);
    scores_kernel<<<N, 384, 0, stream>>>(WH, a3, SS, SD, N, 6, 121, 726);
    for (int h = 0; h < 6; h++) {
        int mode = (h == 0) ? 0 : (h == 5) ? 2 : 1;
        agg121_kernel<<<N, 64, 0, stream>>>(WH, rowptr, esrc, SS, SD, out, h, mode);
    }
}

// Round 2
// 1118.623 us; speedup vs baseline: 1.8351x; 1.8351x over previous
//
#include <hip/hip_runtime.h>
#include <cstdint>

#define N_NODES 20000
#define N_EDGES 320000
#define ALPHA 0.2f
#define GAT_EPS 1e-16f
#define MPAD 20096           // 157 * 128
#define GEMM_K 1024

typedef __attribute__((ext_vector_type(8))) short short8;
typedef __attribute__((ext_vector_type(4))) float f32x4;

__device__ __forceinline__ float elu1(float x) { return x > 0.f ? x : __expf(x) - 1.f; }

__device__ __forceinline__ float bf2f(unsigned short u) {
    unsigned int x = ((unsigned int)u) << 16;
    float f; __builtin_memcpy(&f, &x, 4); return f;
}
__device__ __forceinline__ unsigned short f2bf(float f) {
    unsigned int x; __builtin_memcpy(&x, &f, 4);
    unsigned int r = (x + 0x7fffu + ((x >> 16) & 1u)) >> 16;
    return (unsigned short)r;
}

__device__ __forceinline__ void async16(const unsigned short* g, unsigned short* l) {
    __builtin_amdgcn_global_load_lds(
        (const __attribute__((address_space(1))) unsigned int*)g,
        (__attribute__((address_space(3))) unsigned int*)l, 16, 0, 0);
}

// ---------------- CSR build ----------------
__global__ void hist_kernel(const int* __restrict__ dst, int* __restrict__ counts, int E) {
    int e = blockIdx.x * blockDim.x + threadIdx.x;
    if (e < E) atomicAdd(&counts[dst[e]], 1);
}

__global__ void scan_kernel(const int* __restrict__ counts, int* __restrict__ rowptr,
                            int* __restrict__ cursor, int N) {
    __shared__ int sh[1024];
    int tid = threadIdx.x;
    int offset = 0;
    for (int base = 0; base < N; base += 1024) {
        int i = base + tid;
        int v = (i < N) ? counts[i] : 0;
        sh[tid] = v;
        __syncthreads();
        for (int d = 1; d < 1024; d <<= 1) {
            int t = (tid >= d) ? sh[tid - d] : 0;
            __syncthreads();
            sh[tid] += t;
            __syncthreads();
        }
        int excl = sh[tid] - v;
        if (i < N) { rowptr[i] = offset + excl; cursor[i] = offset + excl; }
        int tot = sh[1023];
        __syncthreads();
        offset += tot;
    }
    if (tid == 0) rowptr[N] = offset;
}

__global__ void scatter_kernel(const int* __restrict__ src, const int* __restrict__ dst,
                               int* __restrict__ cursor, int* __restrict__ esrc, int E) {
    int e = blockIdx.x * blockDim.x + threadIdx.x;
    if (e < E) {
        int p = atomicAdd(&cursor[dst[e]], 1);
        esrc[p] = src[e];
    }
}

// ---------------- fp32 GEMM (layer 1 only, K=50) ----------------
#define BM 128
#define BN 128
#define BK 16
__global__ __launch_bounds__(256) void gemm_f32(const float* __restrict__ A,
                                                const float* __restrict__ B,
                                                float* __restrict__ C,
                                                int M, int K, int Ntot, int Fout) {
    __shared__ float As[BK][BM + 4];
    __shared__ float Bs[BK][BN + 4];
    int tid = threadIdx.x;
    int row0 = blockIdx.y * BM, col0 = blockIdx.x * BN;
    int tr = tid >> 4, tc = tid & 15;
    int ar = tid >> 1, ac = (tid & 1) * 8;
    int br = tid >> 4, bc = (tid & 15) * 8;
    float acc[8][8] = {};
    for (int k0 = 0; k0 < K; k0 += BK) {
        int arow = row0 + ar;
        float av[8] = {0, 0, 0, 0, 0, 0, 0, 0};
        if (arow < M) {
            const float* Ap = A + (size_t)arow * K + k0 + ac;
#pragma unroll
            for (int i = 0; i < 8; i++)
                if (k0 + ac + i < K) av[i] = Ap[i];
        }
#pragma unroll
        for (int i = 0; i < 8; i++) As[ac + i][ar] = av[i];
        int kb = k0 + br;
#pragma unroll
        for (int j = 0; j < 8; j++) {
            int c = col0 + bc + j;
            float v = 0.f;
            if (kb < K && c < Ntot) {
                int h = c / Fout;
                int f = c - h * Fout;
                v = B[(size_t)h * K * Fout + (size_t)kb * Fout + f];
            }
            Bs[br][bc + j] = v;
        }
        __syncthreads();
#pragma unroll
        for (int kk = 0; kk < BK; kk++) {
            float a8[8], b8[8];
#pragma unroll
            for (int i = 0; i < 8; i++) a8[i] = As[kk][tr * 8 + i];
#pragma unroll
            for (int j = 0; j < 8; j++) b8[j] = Bs[kk][tc * 8 + j];
#pragma unroll
            for (int i = 0; i < 8; i++)
#pragma unroll
                for (int j = 0; j < 8; j++) acc[i][j] += a8[i] * b8[j];
        }
        __syncthreads();
    }
#pragma unroll
    for (int i = 0; i < 8; i++) {
        int r = row0 + tr * 8 + i;
        if (r >= M) continue;
#pragma unroll
        for (int j = 0; j < 8; j++) {
            int c = col0 + tc * 8 + j;
            if (c < Ntot) C[(size_t)r * Ntot + c] = acc[i][j];
        }
    }
}

// ---------------- pack W -> Bt bf16 [Cpad][1024], Bt[c][k] = W[h][k][f] ----------------
__global__ void pack_bt(const float* __restrict__ W, unsigned short* __restrict__ Bt,
                        int F, int Ctot) {
    int c = blockIdx.y;
    int k = blockIdx.x * blockDim.x + threadIdx.x;
    float v = 0.f;
    if (c < Ctot) {
        int h = c / F, f = c - h * F;
        v = W[(size_t)h * GEMM_K * F + (size_t)k * F + f];
    }
    Bt[(size_t)c * GEMM_K + k] = f2bf(v);
}

// ---------------- split-bf16 MFMA GEMM: C = (AH+AL) @ BT^T ----------------
// AH/AL: [MPAD][1024] bf16 (hi/lo). BT: [Cpad][1024] bf16 (BT[c][k]).
// C: [M][Ntot] fp32. grid: (ceil(Npad/128), 157), block 256.
__global__ __launch_bounds__(256) void gemm_bf16_split(const unsigned short* __restrict__ AH,
                                                       const unsigned short* __restrict__ AL,
                                                       const unsigned short* __restrict__ BT,
                                                       float* __restrict__ C,
                                                       int M, int Ntot) {
    __shared__ __align__(16) unsigned short sAH[128 * 32];
    __shared__ __align__(16) unsigned short sAL[128 * 32];
    __shared__ __align__(16) unsigned short sBT[128 * 32];
    int t = threadIdx.x;
    int row0 = blockIdx.y * 128, col0 = blockIdx.x * 128;
    int lane = t & 63, wave = t >> 6;
    int wm = wave >> 1, wn = wave & 1;
    int fr = lane & 15;          // m (A) / n (B)
    int fk = (lane >> 4) * 8;    // k offset within 32
    int r0 = t >> 2, cg = (t & 3) * 8;

    const unsigned short* gA = AH + (size_t)row0 * GEMM_K;
    const unsigned short* gL = AL + (size_t)row0 * GEMM_K;
    const unsigned short* gB = BT + (size_t)col0 * GEMM_K;

    f32x4 acc[4][4] = {};

    for (int k0 = 0; k0 < GEMM_K; k0 += 32) {
        __syncthreads();
        const unsigned short* pa = gA + r0 * GEMM_K + k0 + cg;
        const unsigned short* pl = gL + r0 * GEMM_K + k0 + cg;
        const unsigned short* pb = gB + r0 * GEMM_K + k0 + cg;
        async16(pa, sAH + t * 8);
        async16(pa + 64 * GEMM_K, sAH + 2048 + t * 8);
        async16(pl, sAL + t * 8);
        async16(pl + 64 * GEMM_K, sAL + 2048 + t * 8);
        async16(pb, sBT + t * 8);
        async16(pb + 64 * GEMM_K, sBT + 2048 + t * 8);
        __syncthreads();

        short8 ah[4], al[4], bh[4];
#pragma unroll
        for (int mt = 0; mt < 4; mt++) {
            const unsigned short* p = sAH + (wm * 64 + mt * 16 + fr) * 32 + fk;
            ah[mt] = *(const short8*)p;
            al[mt] = *(const short8*)(sAL + (wm * 64 + mt * 16 + fr) * 32 + fk);
        }
#pragma unroll
        for (int nt = 0; nt < 4; nt++)
            bh[nt] = *(const short8*)(sBT + (wn * 64 + nt * 16 + fr) * 32 + fk);
#pragma unroll
        for (int mt = 0; mt < 4; mt++)
#pragma unroll
            for (int nt = 0; nt < 4; nt++) {
                acc[mt][nt] = __builtin_amdgcn_mfma_f32_16x16x32_bf16(ah[mt], bh[nt], acc[mt][nt], 0, 0, 0);
                acc[mt][nt] = __builtin_amdgcn_mfma_f32_16x16x32_bf16(al[mt], bh[nt], acc[mt][nt], 0, 0, 0);
            }
    }

    int rbase = row0 + wm * 64 + ((lane >> 4) << 2);
    int cbase = col0 + wn * 64 + (lane & 15);
#pragma unroll
    for (int mt = 0; mt < 4; mt++)
#pragma unroll
        for (int nt = 0; nt < 4; nt++) {
            int gc = cbase + nt * 16;
            if (gc >= Ntot) continue;
#pragma unroll
            for (int r = 0; r < 4; r++) {
                int gr = rbase + mt * 16 + r;
                if (gr < M) C[(size_t)gr * Ntot + gc] = acc[mt][nt][r];
            }
        }
}

// ---------------- attention scores ----------------
__global__ void scores_kernel(const float* __restrict__ Wh, const float* __restrict__ a,
                              float* __restrict__ ssrc, float* __restrict__ sdst,
                              int N, int H, int Fout, int Ntot) {
    int n = blockIdx.x;
    int h = threadIdx.x >> 6;
    int lane = threadIdx.x & 63;
    if (h >= H) return;
    const float* row = Wh + (size_t)n * Ntot + h * Fout;
    const float* ah = a + (size_t)h * 2 * Fout;
    float s0 = 0.f, s1 = 0.f;
    for (int f = lane; f < Fout; f += 64) {
        float w = row[f];
        s0 += w * ah[f];
        s1 += w * ah[Fout + f];
    }
#pragma unroll
    for (int off = 32; off; off >>= 1) {
        s0 += __shfl_down(s0, off);
        s1 += __shfl_down(s1, off);
    }
    if (lane == 0) {
        ssrc[(size_t)h * N + n] = s0;
        sdst[(size_t)h * N + n] = s1;
    }
}

// ---------------- segment softmax + aggregate (Fout=256), writes bf16 hi/lo ----------------
__global__ __launch_bounds__(64) void agg256_kernel(const float* __restrict__ Wh,
                                                    const int* __restrict__ rowptr,
                                                    const int* __restrict__ esrc,
                                                    const float* __restrict__ ssrc,
                                                    const float* __restrict__ sdst,
                                                    unsigned short* __restrict__ outH,
                                                    unsigned short* __restrict__ outL,
                                                    int use_skip, int N) {
    int n = blockIdx.x, h = blockIdx.y, lane = threadIdx.x;
    int start = rowptr[n], end = rowptr[n + 1];
    const float* ss = ssrc + (size_t)h * N;
    float sd = sdst[(size_t)h * N + n];
    float m = -INFINITY;
    for (int e = start + lane; e < end; e += 64) {
        float sc = ss[esrc[e]] + sd;
        sc = sc > 0.f ? sc : ALPHA * sc;
        m = fmaxf(m, sc);
    }
#pragma unroll
    for (int off = 32; off; off >>= 1) m = fmaxf(m, __shfl_down(m, off));
    m = __shfl(m, 0);

    float acc0 = 0.f, acc1 = 0.f, acc2 = 0.f, acc3 = 0.f;
    float psum = 0.f;
    const float* base = Wh + (size_t)h * 256 + lane * 4;
    for (int e = start; e < end; e++) {
        int s = esrc[e];
        float sc = ss[s] + sd;
        sc = sc > 0.f ? sc : ALPHA * sc;
        float p = __expf(sc - m);
        psum += p;
        const float4 w = *(const float4*)(base + (size_t)s * 1024);
        acc0 += p * w.x; acc1 += p * w.y; acc2 += p * w.z; acc3 += p * w.w;
    }
    float inv = 1.f / (psum + GAT_EPS);
    size_t o = (size_t)n * 1024 + h * 256 + lane * 4;
    float v[4] = {acc0 * inv, acc1 * inv, acc2 * inv, acc3 * inv};
    if (use_skip) {
        ushort4 vh = *(const ushort4*)(outH + o);
        ushort4 vl = *(const ushort4*)(outL + o);
        v[0] = elu1(elu1(v[0]) + bf2f(vh.x) + bf2f(vl.x));
        v[1] = elu1(elu1(v[1]) + bf2f(vh.y) + bf2f(vl.y));
        v[2] = elu1(elu1(v[2]) + bf2f(vh.z) + bf2f(vl.z));
        v[3] = elu1(elu1(v[3]) + bf2f(vh.w) + bf2f(vl.w));
    } else {
#pragma unroll
        for (int i = 0; i < 4; i++) v[i] = elu1(elu1(v[i]));
    }
    ushort4 wh, wl;
    wh.x = f2bf(v[0]); wl.x = f2bf(v[0] - bf2f(wh.x));
    wh.y = f2bf(v[1]); wl.y = f2bf(v[1] - bf2f(wh.y));
    wh.z = f2bf(v[2]); wl.z = f2bf(v[2] - bf2f(wh.z));
    wh.w = f2bf(v[3]); wl.w = f2bf(v[3] - bf2f(wh.w));
    *(ushort4*)(outH + o) = wh;
    *(ushort4*)(outL + o) = wl;
}

// ---------------- layer 3 aggregate (Fout=121) ----------------
__global__ __launch_bounds__(64) void agg121_kernel(const float* __restrict__ Wh,
                                                    const int* __restrict__ rowptr,
                                                    const int* __restrict__ esrc,
                                                    const float* __restrict__ ssrc,
                                                    const float* __restrict__ sdst,
                                                    float* __restrict__ out, int head, int mode) {
    int n = blockIdx.x, lane = threadIdx.x;
    int start = rowptr[n], end = rowptr[n + 1];
    const float* ss = ssrc + (size_t)head * N_NODES;
    float sd = sdst[(size_t)head * N_NODES + n];
    float m = -INFINITY;
    for (int e = start + lane; e < end; e += 64) {
        float sc = ss[esrc[e]] + sd;
        sc = sc > 0.f ? sc : ALPHA * sc;
        m = fmaxf(m, sc);
    }
#pragma unroll
    for (int off = 32; off; off >>= 1) m = fmaxf(m, __shfl_down(m, off));
    m = __shfl(m, 0);

    float acc0 = 0.f, acc1 = 0.f, psum = 0.f;
    const float* base = Wh + (size_t)head * 121;
    for (int e = start; e < end; e++) {
        int s = esrc[e];
        float sc = ss[s] + sd;
        sc = sc > 0.f ? sc : ALPHA * sc;
        float p = __expf(sc - m);
        psum += p;
        const float* row = base + (size_t)s * 726;
        acc0 += p * row[lane];
        if (lane < 57) acc1 += p * row[64 + lane];
    }
    float inv = 1.f / (psum + GAT_EPS);
    float v0 = acc0 * inv, v1 = acc1 * inv;
    float* o = out + (size_t)n * 121;
    if (mode == 0) {
        o[lane] = v0;
        if (lane < 57) o[64 + lane] = v1;
    } else if (mode == 1) {
        o[lane] += v0;
        if (lane < 57) o[64 + lane] += v1;
    } else {
        float x0 = (o[lane] + v0) * (1.f / 6.f);
        o[lane] = 1.f / (1.f + __expf(-x0));
        if (lane < 57) {
            float x1 = (o[64 + lane] + v1) * (1.f / 6.f);
            o[64 + lane] = 1.f / (1.f + __expf(-x1));
        }
    }
}

extern "C" void kernel_launch(void* const* d_in, const int* in_sizes, int n_in,
                              void* d_out, int out_size, void* d_ws, size_t ws_size,
                              hipStream_t stream) {
    const float* x  = (const float*)d_in[0];
    const int*   ei = (const int*)d_in[1];
    const float* W1 = (const float*)d_in[2];
    const float* a1 = (const float*)d_in[3];
    const float* W2 = (const float*)d_in[4];
    const float* a2 = (const float*)d_in[5];
    const float* W3 = (const float*)d_in[6];
    const float* a3 = (const float*)d_in[7];
    float* out = (float*)d_out;
    const int N = N_NODES, E = N_EDGES;
    const int* src = ei;
    const int* dst = ei + E;

    char* ws = (char*)d_ws;
    size_t off = 0;
    auto alloc = [&](size_t b) { size_t o = off; off += (b + 255) & ~(size_t)255; return o; };
    unsigned short* AH = (unsigned short*)(ws + alloc((size_t)MPAD * 1024 * 2)); // x hi
    unsigned short* AL = (unsigned short*)(ws + alloc((size_t)MPAD * 1024 * 2)); // x lo
    float* WH     = (float*)(ws + alloc((size_t)N * 1024 * 4));                  // per-layer Wh
    unsigned short* BT = (unsigned short*)(ws + alloc((size_t)1024 * 1024 * 2)); // W^T bf16
    float* SS     = (float*)(ws + alloc((size_t)6 * N * 4));
    float* SD     = (float*)(ws + alloc((size_t)6 * N * 4));
    int*   rowptr = (int*)(ws + alloc((size_t)(N + 1) * 4));
    int*   cursor = (int*)(ws + alloc((size_t)N * 4));
    int*   counts = (int*)(ws + alloc((size_t)N * 4));
    int*   esrc   = (int*)(ws + alloc((size_t)E * 4));

    // CSR by dst
    hipMemsetAsync(counts, 0, (size_t)N * 4, stream);
    hist_kernel<<<(E + 255) / 256, 256, 0, stream>>>(dst, counts, E);
    scan_kernel<<<1, 1024, 0, stream>>>(counts, rowptr, cursor, N);
    scatter_kernel<<<(E + 255) / 256, 256, 0, stream>>>(src, dst, cursor, esrc, E);
    // zero the M-pad rows of AH/AL (rows 20000..20095)
    hipMemsetAsync(AH + (size_t)N * 1024, 0, (size_t)(MPAD - N) * 1024 * 2, stream);
    hipMemsetAsync(AL + (size_t)N * 1024, 0, (size_t)(MPAD - N) * 1024 * 2, stream);

    // ---- layer 1: 50 -> 4x256 concat (fp32 GEMM, cheap K) ----
    gemm_f32<<<dim3(8, 157), 256, 0, stream>>>(x, W1, WH, N, 50, 1024, 256);
    scores_kernel<<<N, 256, 0, stream>>>(WH, a1, SS, SD, N, 4, 256, 1024);
    agg256_kernel<<<dim3(N, 4), 64, 0, stream>>>(WH, rowptr, esrc, SS, SD, AH, AL, 0, N);

    // ---- layer 2: 1024 -> 4x256 concat + skip (split-bf16 MFMA) ----
    pack_bt<<<dim3(4, 1024), 256, 0, stream>>>(W2, BT, 256, 1024);
    gemm_bf16_split<<<dim3(8, 157), 256, 0, stream>>>(AH, AL, BT, WH, N, 1024);
    scores_kernel<<<N, 256, 0, stream>>>(WH, a2, SS, SD, N, 4, 256, 1024);
    agg256_kernel<<<dim3(N, 4), 64, 0, stream>>>(WH, rowptr, esrc, SS, SD, AH, AL, 1, N);

    // ---- layer 3: 1024 -> 6x121, mean over heads, sigmoid ----
    pack_bt<<<dim3(4, 768), 256, 0, stream>>>(W3, BT, 121, 726);
    gemm_bf16_split<<<dim3(6, 157), 256, 0, stream>>>(AH, AL, BT, WH, N, 726);
    scores_kernel<<<N, 384, 0, stream>>>(WH, a3, SS, SD, N, 6, 121, 726);
    for (int h = 0; h < 6; h++) {
        int mode = (h == 0) ? 0 : (h == 5) ? 2 : 1;
        agg121_kernel<<<N, 64, 0, stream>>>(WH, rowptr, esrc, SS, SD, out, h, mode);
    }
}

// Round 3
// 723.093 us; speedup vs baseline: 2.8389x; 1.5470x over previous
//
#include <hip/hip_runtime.h>
#include <cstdint>

#define N_NODES 20000
#define N_EDGES 320000
#define ALPHA 0.2f
#define GAT_EPS 1e-16f
#define MPAD 20096           // 157 * 128
#define GEMM_K 1024

typedef __attribute__((ext_vector_type(8))) _Float16 half8;
typedef __attribute__((ext_vector_type(4))) _Float16 half4;
typedef __attribute__((ext_vector_type(4))) float f32x4;

__device__ __forceinline__ float elu1(float x) { return x > 0.f ? x : __expf(x) - 1.f; }

__device__ __forceinline__ void async16(const void* g, void* l) {
    __builtin_amdgcn_global_load_lds(
        (const __attribute__((address_space(1))) unsigned int*)g,
        (__attribute__((address_space(3))) unsigned int*)l, 16, 0, 0);
}

// ---------------- CSR build ----------------
__global__ void hist_kernel(const int* __restrict__ dst, int* __restrict__ counts, int E) {
    int e = blockIdx.x * blockDim.x + threadIdx.x;
    if (e < E) atomicAdd(&counts[dst[e]], 1);
}

__global__ void scan_kernel(const int* __restrict__ counts, int* __restrict__ rowptr,
                            int* __restrict__ cursor, int N) {
    __shared__ int sh[1024];
    int tid = threadIdx.x;
    int offset = 0;
    for (int base = 0; base < N; base += 1024) {
        int i = base + tid;
        int v = (i < N) ? counts[i] : 0;
        sh[tid] = v;
        __syncthreads();
        for (int d = 1; d < 1024; d <<= 1) {
            int t = (tid >= d) ? sh[tid - d] : 0;
            __syncthreads();
            sh[tid] += t;
            __syncthreads();
        }
        int excl = sh[tid] - v;
        if (i < N) { rowptr[i] = offset + excl; cursor[i] = offset + excl; }
        int tot = sh[1023];
        __syncthreads();
        offset += tot;
    }
    if (tid == 0) rowptr[N] = offset;
}

__global__ void scatter_kernel(const int* __restrict__ src, const int* __restrict__ dst,
                               int* __restrict__ cursor, int* __restrict__ esrc, int E) {
    int e = blockIdx.x * blockDim.x + threadIdx.x;
    if (e < E) {
        int p = atomicAdd(&cursor[dst[e]], 1);
        esrc[p] = src[e];
    }
}

// ---------------- fp32 GEMM (layer 1, K=50), fp16 output ----------------
#define BM 128
#define BN 128
#define BK 16
__global__ __launch_bounds__(256) void gemm_f32(const float* __restrict__ A,
                                                const float* __restrict__ B,
                                                _Float16* __restrict__ C,
                                                int M, int K, int Ntot, int Fout, int ld) {
    __shared__ float As[BK][BM + 4];
    __shared__ float Bs[BK][BN + 4];
    int tid = threadIdx.x;
    int row0 = blockIdx.y * BM, col0 = blockIdx.x * BN;
    int tr = tid >> 4, tc = tid & 15;
    int ar = tid >> 1, ac = (tid & 1) * 8;
    int br = tid >> 4, bc = (tid & 15) * 8;
    float acc[8][8] = {};
    for (int k0 = 0; k0 < K; k0 += BK) {
        int arow = row0 + ar;
        float av[8] = {0, 0, 0, 0, 0, 0, 0, 0};
        if (arow < M) {
            const float* Ap = A + (size_t)arow * K + k0 + ac;
#pragma unroll
            for (int i = 0; i < 8; i++)
                if (k0 + ac + i < K) av[i] = Ap[i];
        }
#pragma unroll
        for (int i = 0; i < 8; i++) As[ac + i][ar] = av[i];
        int kb = k0 + br;
#pragma unroll
        for (int j = 0; j < 8; j++) {
            int c = col0 + bc + j;
            float v = 0.f;
            if (kb < K && c < Ntot) {
                int h = c / Fout;
                int f = c - h * Fout;
                v = B[(size_t)h * K * Fout + (size_t)kb * Fout + f];
            }
            Bs[br][bc + j] = v;
        }
        __syncthreads();
#pragma unroll
        for (int kk = 0; kk < BK; kk++) {
            float a8[8], b8[8];
#pragma unroll
            for (int i = 0; i < 8; i++) a8[i] = As[kk][tr * 8 + i];
#pragma unroll
            for (int j = 0; j < 8; j++) b8[j] = Bs[kk][tc * 8 + j];
#pragma unroll
            for (int i = 0; i < 8; i++)
#pragma unroll
                for (int j = 0; j < 8; j++) acc[i][j] += a8[i] * b8[j];
        }
        __syncthreads();
    }
#pragma unroll
    for (int i = 0; i < 8; i++) {
        int r = row0 + tr * 8 + i;
        if (r >= M) continue;
#pragma unroll
        for (int j = 0; j < 8; j++) {
            int c = col0 + tc * 8 + j;
            if (c < Ntot) C[(size_t)r * ld + c] = (_Float16)acc[i][j];
        }
    }
}

// ---------------- pack W (fp32) -> BT fp16 [Cpad][1024] ----------------
__global__ void pack_bt16(const float* __restrict__ W, _Float16* __restrict__ Bt,
                          int F, int Ctot) {
    int c = blockIdx.y;
    int k = blockIdx.x * blockDim.x + threadIdx.x;
    float v = 0.f;
    if (c < Ctot) {
        int h = c / F, f = c - h * F;
        v = W[(size_t)h * GEMM_K * F + (size_t)k * F + f];
    }
    Bt[(size_t)c * GEMM_K + k] = (_Float16)v;
}

// ---------------- fp16 MFMA GEMM: C[M][Ntot](fp16, ld) = A[MPAD][1024] @ BT^T ----------------
__global__ __launch_bounds__(256) void gemm_f16(const _Float16* __restrict__ A,
                                                const _Float16* __restrict__ BT,
                                                _Float16* __restrict__ C,
                                                int M, int Ntot, int ld) {
    __shared__ __align__(16) _Float16 sA[128 * 32];
    __shared__ __align__(16) _Float16 sB[128 * 32];
    int t = threadIdx.x;
    int row0 = blockIdx.y * 128, col0 = blockIdx.x * 128;
    int lane = t & 63, wave = t >> 6;
    int wm = wave >> 1, wn = wave & 1;
    int fr = lane & 15;
    int fk = (lane >> 4) * 8;
    int r0 = t >> 2, cg = (t & 3) * 8;

    const _Float16* gA = A + (size_t)row0 * GEMM_K;
    const _Float16* gB = BT + (size_t)col0 * GEMM_K;

    f32x4 acc[4][4] = {};

    for (int k0 = 0; k0 < GEMM_K; k0 += 32) {
        __syncthreads();
        const _Float16* pa = gA + r0 * GEMM_K + k0 + cg;
        const _Float16* pb = gB + r0 * GEMM_K + k0 + cg;
        async16(pa, sA + t * 8);
        async16(pa + 64 * GEMM_K, sA + 2048 + t * 8);
        async16(pb, sB + t * 8);
        async16(pb + 64 * GEMM_K, sB + 2048 + t * 8);
        __syncthreads();

        half8 af[4], bf[4];
#pragma unroll
        for (int mt = 0; mt < 4; mt++)
            af[mt] = *(const half8*)(sA + (wm * 64 + mt * 16 + fr) * 32 + fk);
#pragma unroll
        for (int nt = 0; nt < 4; nt++)
            bf[nt] = *(const half8*)(sB + (wn * 64 + nt * 16 + fr) * 32 + fk);
#pragma unroll
        for (int mt = 0; mt < 4; mt++)
#pragma unroll
            for (int nt = 0; nt < 4; nt++)
                acc[mt][nt] = __builtin_amdgcn_mfma_f32_16x16x32_f16(af[mt], bf[nt], acc[mt][nt], 0, 0, 0);
    }

    int rbase = row0 + wm * 64 + ((lane >> 4) << 2);
    int cbase = col0 + wn * 64 + (lane & 15);
#pragma unroll
    for (int mt = 0; mt < 4; mt++)
#pragma unroll
        for (int nt = 0; nt < 4; nt++) {
            int gc = cbase + nt * 16;
            if (gc >= Ntot) continue;
#pragma unroll
            for (int r = 0; r < 4; r++) {
                int gr = rbase + mt * 16 + r;
                if (gr < M) C[(size_t)gr * ld + gc] = (_Float16)acc[mt][nt][r];
            }
        }
}

// ---------------- attention scores (fp16 Wh) ----------------
__global__ void scores_kernel(const _Float16* __restrict__ Wh, const float* __restrict__ a,
                              float* __restrict__ ssrc, float* __restrict__ sdst,
                              int N, int H, int Fout, int ld) {
    int n = blockIdx.x;
    int h = threadIdx.x >> 6;
    int lane = threadIdx.x & 63;
    if (h >= H) return;
    const _Float16* row = Wh + (size_t)n * ld + h * Fout;
    const float* ah = a + (size_t)h * 2 * Fout;
    float s0 = 0.f, s1 = 0.f;
    for (int f = lane; f < Fout; f += 64) {
        float w = (float)row[f];
        s0 += w * ah[f];
        s1 += w * ah[Fout + f];
    }
#pragma unroll
    for (int off = 32; off; off >>= 1) {
        s0 += __shfl_down(s0, off);
        s1 += __shfl_down(s1, off);
    }
    if (lane == 0) {
        ssrc[(size_t)h * N + n] = s0;
        sdst[(size_t)h * N + n] = s1;
    }
}

// ---------------- per-edge attention weights (CSR order) ----------------
__global__ __launch_bounds__(64) void att_kernel(const int* __restrict__ rowptr,
                                                 const int* __restrict__ esrc,
                                                 const float* __restrict__ SS,
                                                 const float* __restrict__ SD,
                                                 float* __restrict__ ATT, int N, int H) {
    int n = blockIdx.x, lane = threadIdx.x;
    int start = rowptr[n], end = rowptr[n + 1];
    for (int h = 0; h < H; h++) {
        const float* ss = SS + (size_t)h * N;
        float sd = SD[(size_t)h * N + n];
        float* att = ATT + (size_t)h * N_EDGES;
        float m = -INFINITY;
        for (int e = start + lane; e < end; e += 64) {
            float sc = ss[esrc[e]] + sd;
            sc = sc > 0.f ? sc : ALPHA * sc;
            m = fmaxf(m, sc);
        }
#pragma unroll
        for (int off = 32; off; off >>= 1) m = fmaxf(m, __shfl_down(m, off));
        m = __shfl(m, 0);
        float psum = 0.f;
        for (int e = start + lane; e < end; e += 64) {
            float sc = ss[esrc[e]] + sd;
            sc = sc > 0.f ? sc : ALPHA * sc;
            float p = __expf(sc - m);
            psum += p;
            att[e] = p;
        }
#pragma unroll
        for (int off = 32; off; off >>= 1) psum += __shfl_down(psum, off);
        psum = __shfl(psum, 0);
        float inv = 1.f / (psum + GAT_EPS);
        for (int e = start + lane; e < end; e += 64) att[e] *= inv;
    }
}

// ---------------- aggregate Fout=256 layers (fp16 gather, prenormalized att) ----------------
__global__ __launch_bounds__(64) void agg256_kernel(const _Float16* __restrict__ WH16,
                                                    const int* __restrict__ rowptr,
                                                    const int* __restrict__ esrc,
                                                    const float* __restrict__ ATT,
                                                    _Float16* __restrict__ X16,
                                                    int use_skip, int N) {
    int n = blockIdx.x, h = blockIdx.y, lane = threadIdx.x;
    int start = rowptr[n], end = rowptr[n + 1];
    const float* ap = ATT + (size_t)h * N_EDGES;
    int base = h * 256 + lane * 4;
    float a0 = 0.f, a1 = 0.f, a2 = 0.f, a3 = 0.f;
    int e = start;
    for (; e + 4 <= end; e += 4) {
        int s0 = esrc[e], s1 = esrc[e + 1], s2 = esrc[e + 2], s3 = esrc[e + 3];
        float p0 = ap[e], p1 = ap[e + 1], p2 = ap[e + 2], p3 = ap[e + 3];
        half4 w0 = *(const half4*)(WH16 + (size_t)s0 * 1024 + base);
        half4 w1 = *(const half4*)(WH16 + (size_t)s1 * 1024 + base);
        half4 w2 = *(const half4*)(WH16 + (size_t)s2 * 1024 + base);
        half4 w3 = *(const half4*)(WH16 + (size_t)s3 * 1024 + base);
        a0 += p0 * (float)w0.x + p1 * (float)w1.x + p2 * (float)w2.x + p3 * (float)w3.x;
        a1 += p0 * (float)w0.y + p1 * (float)w1.y + p2 * (float)w2.y + p3 * (float)w3.y;
        a2 += p0 * (float)w0.z + p1 * (float)w1.z + p2 * (float)w2.z + p3 * (float)w3.z;
        a3 += p0 * (float)w0.w + p1 * (float)w1.w + p2 * (float)w2.w + p3 * (float)w3.w;
    }
    for (; e < end; e++) {
        int s = esrc[e];
        float p = ap[e];
        half4 w = *(const half4*)(WH16 + (size_t)s * 1024 + base);
        a0 += p * (float)w.x; a1 += p * (float)w.y;
        a2 += p * (float)w.z; a3 += p * (float)w.w;
    }
    float v[4] = {a0, a1, a2, a3};
    size_t o = (size_t)n * 1024 + base;
    if (use_skip) {
        half4 sk = *(const half4*)(X16 + o);
        v[0] = elu1(elu1(v[0]) + (float)sk.x);
        v[1] = elu1(elu1(v[1]) + (float)sk.y);
        v[2] = elu1(elu1(v[2]) + (float)sk.z);
        v[3] = elu1(elu1(v[3]) + (float)sk.w);
    } else {
#pragma unroll
        for (int i = 0; i < 4; i++) v[i] = elu1(elu1(v[i]));
    }
    half4 r;
    r.x = (_Float16)v[0]; r.y = (_Float16)v[1];
    r.z = (_Float16)v[2]; r.w = (_Float16)v[3];
    *(half4*)(X16 + o) = r;
}

// ---------------- layer 3: all 6 heads fused, mean + sigmoid ----------------
__global__ __launch_bounds__(128) void agg726_kernel(const _Float16* __restrict__ WH16,
                                                     const int* __restrict__ rowptr,
                                                     const int* __restrict__ esrc,
                                                     const float* __restrict__ ATT,
                                                     float* __restrict__ out, int N) {
    __shared__ float part[2][128];
    int t = threadIdx.x, n = blockIdx.x;
    int lane = t & 63, wv = t >> 6;
    int h0 = wv * 3;
    int start = rowptr[n], end = rowptr[n + 1];
    float acc[3][2] = {};
    for (int e = start; e < end; e++) {
        int s = esrc[e];
        float p0 = ATT[(size_t)(h0 + 0) * N_EDGES + e];
        float p1 = ATT[(size_t)(h0 + 1) * N_EDGES + e];
        float p2 = ATT[(size_t)(h0 + 2) * N_EDGES + e];
        const _Float16* row = WH16 + (size_t)s * 768 + h0 * 121;
        acc[0][0] += p0 * (float)row[lane];
        acc[1][0] += p1 * (float)row[121 + lane];
        acc[2][0] += p2 * (float)row[242 + lane];
        if (lane < 57) {
            acc[0][1] += p0 * (float)row[64 + lane];
            acc[1][1] += p1 * (float)row[185 + lane];
            acc[2][1] += p2 * (float)row[306 + lane];
        }
    }
    float s0 = acc[0][0] + acc[1][0] + acc[2][0];
    float s1 = acc[0][1] + acc[1][1] + acc[2][1];
    part[wv][lane] = s0;
    if (lane < 57) part[wv][64 + lane] = s1;
    __syncthreads();
    if (t < 121) {
        float tot = (part[0][t] + part[1][t]) * (1.f / 6.f);
        out[(size_t)n * 121 + t] = 1.f / (1.f + __expf(-tot));
    }
}

extern "C" void kernel_launch(void* const* d_in, const int* in_sizes, int n_in,
                              void* d_out, int out_size, void* d_ws, size_t ws_size,
                              hipStream_t stream) {
    const float* x  = (const float*)d_in[0];
    const int*   ei = (const int*)d_in[1];
    const float* W1 = (const float*)d_in[2];
    const float* a1 = (const float*)d_in[3];
    const float* W2 = (const float*)d_in[4];
    const float* a2 = (const float*)d_in[5];
    const float* W3 = (const float*)d_in[6];
    const float* a3 = (const float*)d_in[7];
    float* out = (float*)d_out;
    const int N = N_NODES, E = N_EDGES;
    const int* src = ei;
    const int* dst = ei + E;

    char* ws = (char*)d_ws;
    size_t off = 0;
    auto alloc = [&](size_t b) { size_t o = off; off += (b + 255) & ~(size_t)255; return o; };
    _Float16* X16  = (_Float16*)(ws + alloc((size_t)MPAD * 1024 * 2)); // x1 then x2
    _Float16* WH16 = (_Float16*)(ws + alloc((size_t)MPAD * 1024 * 2)); // per-layer Wh
    _Float16* BT16 = (_Float16*)(ws + alloc((size_t)1024 * 1024 * 2)); // W^T fp16
    float* SS     = (float*)(ws + alloc((size_t)6 * N * 4));
    float* SD     = (float*)(ws + alloc((size_t)6 * N * 4));
    float* ATT    = (float*)(ws + alloc((size_t)6 * E * 4));
    int*   rowptr = (int*)(ws + alloc((size_t)(N + 1) * 4));
    int*   cursor = (int*)(ws + alloc((size_t)N * 4));
    int*   counts = (int*)(ws + alloc((size_t)N * 4));
    int*   esrc   = (int*)(ws + alloc((size_t)E * 4));

    // CSR by dst
    hipMemsetAsync(counts, 0, (size_t)N * 4, stream);
    hist_kernel<<<(E + 255) / 256, 256, 0, stream>>>(dst, counts, E);
    scan_kernel<<<1, 1024, 0, stream>>>(counts, rowptr, cursor, N);
    scatter_kernel<<<(E + 255) / 256, 256, 0, stream>>>(src, dst, cursor, esrc, E);
    // zero GEMM pad rows (rows 20000..20095) of X16
    hipMemsetAsync(X16 + (size_t)N * 1024, 0, (size_t)(MPAD - N) * 1024 * 2, stream);

    // ---- layer 1: 50 -> 4x256 concat (fp32 vector GEMM) ----
    gemm_f32<<<dim3(8, 157), 256, 0, stream>>>(x, W1, WH16, N, 50, 1024, 256, 1024);
    scores_kernel<<<N, 256, 0, stream>>>(WH16, a1, SS, SD, N, 4, 256, 1024);
    att_kernel<<<N, 64, 0, stream>>>(rowptr, esrc, SS, SD, ATT, N, 4);
    agg256_kernel<<<dim3(N, 4), 64, 0, stream>>>(WH16, rowptr, esrc, ATT, X16, 0, N);

    // ---- layer 2: 1024 -> 4x256 concat + skip (fp16 MFMA) ----
    pack_bt16<<<dim3(4, 1024), 256, 0, stream>>>(W2, BT16, 256, 1024);
    gemm_f16<<<dim3(8, 157), 256, 0, stream>>>(X16, BT16, WH16, N, 1024, 1024);
    scores_kernel<<<N, 256, 0, stream>>>(WH16, a2, SS, SD, N, 4, 256, 1024);
    att_kernel<<<N, 64, 0, stream>>>(rowptr, esrc, SS, SD, ATT, N, 4);
    agg256_kernel<<<dim3(N, 4), 64, 0, stream>>>(WH16, rowptr, esrc, ATT, X16, 1, N);

    // ---- layer 3: 1024 -> 6x121, mean over heads, sigmoid ----
    pack_bt16<<<dim3(4, 768), 256, 0, stream>>>(W3, BT16, 121, 726);
    gemm_f16<<<dim3(6, 157), 256, 0, stream>>>(X16, BT16, WH16, N, 726, 768);
    scores_kernel<<<N, 384, 0, stream>>>(WH16, a3, SS, SD, N, 6, 121, 768);
    att_kernel<<<N, 64, 0, stream>>>(rowptr, esrc, SS, SD, ATT, N, 6);
    agg726_kernel<<<N, 128, 0, stream>>>(WH16, rowptr, esrc, ATT, out, N);
}

// Round 4
// 687.645 us; speedup vs baseline: 2.9853x; 1.0515x over previous
//
#include <hip/hip_runtime.h>
#include <cstdint>

#define N_NODES 20000
#define N_EDGES 320000
#define ALPHA 0.2f
#define GAT_EPS 1e-16f
#define MPAD 20096           // 157 * 128

typedef __attribute__((ext_vector_type(8))) _Float16 half8;
typedef __attribute__((ext_vector_type(4))) _Float16 half4;
typedef __attribute__((ext_vector_type(2))) _Float16 half2;
typedef __attribute__((ext_vector_type(4))) float f32x4;

__device__ __forceinline__ float elu1(float x) { return x > 0.f ? x : __expf(x) - 1.f; }

__device__ __forceinline__ void async16(const void* g, void* l) {
    __builtin_amdgcn_global_load_lds(
        (const __attribute__((address_space(1))) unsigned int*)g,
        (__attribute__((address_space(3))) unsigned int*)l, 16, 0, 0);
}

// ---------------- CSR build ----------------
__global__ void hist_kernel(const int* __restrict__ dst, int* __restrict__ counts, int E) {
    int e = blockIdx.x * blockDim.x + threadIdx.x;
    if (e < E) atomicAdd(&counts[dst[e]], 1);
}

__global__ void scan_kernel(const int* __restrict__ counts, int* __restrict__ rowptr,
                            int* __restrict__ cursor, int N) {
    __shared__ int sh[1024];
    int tid = threadIdx.x;
    int offset = 0;
    for (int base = 0; base < N; base += 1024) {
        int i = base + tid;
        int v = (i < N) ? counts[i] : 0;
        sh[tid] = v;
        __syncthreads();
        for (int d = 1; d < 1024; d <<= 1) {
            int t = (tid >= d) ? sh[tid - d] : 0;
            __syncthreads();
            sh[tid] += t;
            __syncthreads();
        }
        int excl = sh[tid] - v;
        if (i < N) { rowptr[i] = offset + excl; cursor[i] = offset + excl; }
        int tot = sh[1023];
        __syncthreads();
        offset += tot;
    }
    if (tid == 0) rowptr[N] = offset;
}

__global__ void scatter_kernel(const int* __restrict__ src, const int* __restrict__ dst,
                               int* __restrict__ cursor, int* __restrict__ esrc, int E) {
    int e = blockIdx.x * blockDim.x + threadIdx.x;
    if (e < E) {
        int p = atomicAdd(&cursor[dst[e]], 1);
        esrc[p] = src[e];
    }
}

// ---------------- pack x (fp32, 20000x50) -> A1 fp16 [MPAD][64], K zero-padded ----------------
__global__ void pack_x16(const float* __restrict__ x, _Float16* __restrict__ A) {
    int idx = blockIdx.x * 256 + threadIdx.x;   // MPAD*64
    int r = idx >> 6, c = idx & 63;
    float v = (r < N_NODES && c < 50) ? x[r * 50 + c] : 0.f;
    A[idx] = (_Float16)v;
}

// ---------------- pack W1 (4,50,256) -> BT1 fp16 [1024][64] ----------------
__global__ void pack_bt1(const float* __restrict__ W, _Float16* __restrict__ Bt) {
    int idx = blockIdx.x * 256 + threadIdx.x;   // 1024*64
    int c = idx >> 6, k = idx & 63;
    int h = c >> 8, f = c & 255;
    float v = (k < 50) ? W[((size_t)h * 50 + k) * 256 + f] : 0.f;
    Bt[idx] = (_Float16)v;
}

// ---------------- pack W (fp32, K=1024) -> BT fp16 [Cpad][1024] ----------------
__global__ void pack_bt16(const float* __restrict__ W, _Float16* __restrict__ Bt,
                          int F, int Ctot) {
    int c = blockIdx.y;
    int k = blockIdx.x * blockDim.x + threadIdx.x;
    float v = 0.f;
    if (c < Ctot) {
        int h = c / F, f = c - h * F;
        v = W[(size_t)h * 1024 * F + (size_t)k * F + f];
    }
    Bt[(size_t)c * 1024 + k] = (_Float16)v;
}

// ---------------- fp16 MFMA GEMM: C[M][Ntot](fp16, ld) = A[MPAD][Kdim] @ BT^T ----------------
__global__ __launch_bounds__(256) void gemm_f16(const _Float16* __restrict__ A,
                                                const _Float16* __restrict__ BT,
                                                _Float16* __restrict__ C,
                                                int M, int Ntot, int ld, int Kdim) {
    __shared__ __align__(16) _Float16 sA[128 * 32];
    __shared__ __align__(16) _Float16 sB[128 * 32];
    int t = threadIdx.x;
    int row0 = blockIdx.y * 128, col0 = blockIdx.x * 128;
    int lane = t & 63, wave = t >> 6;
    int wm = wave >> 1, wn = wave & 1;
    int fr = lane & 15;
    int fk = (lane >> 4) * 8;
    int r0 = t >> 2, cg = (t & 3) * 8;

    const _Float16* gA = A + (size_t)row0 * Kdim;
    const _Float16* gB = BT + (size_t)col0 * Kdim;

    f32x4 acc[4][4] = {};

    for (int k0 = 0; k0 < Kdim; k0 += 32) {
        __syncthreads();
        const _Float16* pa = gA + r0 * Kdim + k0 + cg;
        const _Float16* pb = gB + r0 * Kdim + k0 + cg;
        async16(pa, sA + t * 8);
        async16(pa + 64 * Kdim, sA + 2048 + t * 8);
        async16(pb, sB + t * 8);
        async16(pb + 64 * Kdim, sB + 2048 + t * 8);
        __syncthreads();

        half8 af[4], bf[4];
#pragma unroll
        for (int mt = 0; mt < 4; mt++)
            af[mt] = *(const half8*)(sA + (wm * 64 + mt * 16 + fr) * 32 + fk);
#pragma unroll
        for (int nt = 0; nt < 4; nt++)
            bf[nt] = *(const half8*)(sB + (wn * 64 + nt * 16 + fr) * 32 + fk);
#pragma unroll
        for (int mt = 0; mt < 4; mt++)
#pragma unroll
            for (int nt = 0; nt < 4; nt++)
                acc[mt][nt] = __builtin_amdgcn_mfma_f32_16x16x32_f16(af[mt], bf[nt], acc[mt][nt], 0, 0, 0);
    }

    int rbase = row0 + wm * 64 + ((lane >> 4) << 2);
    int cbase = col0 + wn * 64 + (lane & 15);
#pragma unroll
    for (int mt = 0; mt < 4; mt++)
#pragma unroll
        for (int nt = 0; nt < 4; nt++) {
            int gc = cbase + nt * 16;
            if (gc >= Ntot) continue;
#pragma unroll
            for (int r = 0; r < 4; r++) {
                int gr = rbase + mt * 16 + r;
                if (gr < M) C[(size_t)gr * ld + gc] = (_Float16)acc[mt][nt][r];
            }
        }
}

// ---------------- attention scores (fp16 Wh) ----------------
__global__ void scores_kernel(const _Float16* __restrict__ Wh, const float* __restrict__ a,
                              float* __restrict__ ssrc, float* __restrict__ sdst,
                              int N, int H, int Fout, int ld) {
    int n = blockIdx.x;
    int h = threadIdx.x >> 6;
    int lane = threadIdx.x & 63;
    if (h >= H) return;
    const _Float16* row = Wh + (size_t)n * ld + h * Fout;
    const float* ah = a + (size_t)h * 2 * Fout;
    float s0 = 0.f, s1 = 0.f;
    for (int f = lane; f < Fout; f += 64) {
        float w = (float)row[f];
        s0 += w * ah[f];
        s1 += w * ah[Fout + f];
    }
#pragma unroll
    for (int off = 32; off; off >>= 1) {
        s0 += __shfl_down(s0, off);
        s1 += __shfl_down(s1, off);
    }
    if (lane == 0) {
        ssrc[(size_t)h * N + n] = s0;
        sdst[(size_t)h * N + n] = s1;
    }
}

// ---------------- per-edge attention weights (CSR order) ----------------
__global__ __launch_bounds__(64) void att_kernel(const int* __restrict__ rowptr,
                                                 const int* __restrict__ esrc,
                                                 const float* __restrict__ SS,
                                                 const float* __restrict__ SD,
                                                 float* __restrict__ ATT, int N, int H) {
    int n = blockIdx.x, lane = threadIdx.x;
    int start = rowptr[n], end = rowptr[n + 1];
    for (int h = 0; h < H; h++) {
        const float* ss = SS + (size_t)h * N;
        float sd = SD[(size_t)h * N + n];
        float* att = ATT + (size_t)h * N_EDGES;
        float m = -INFINITY;
        for (int e = start + lane; e < end; e += 64) {
            float sc = ss[esrc[e]] + sd;
            sc = sc > 0.f ? sc : ALPHA * sc;
            m = fmaxf(m, sc);
        }
#pragma unroll
        for (int off = 32; off; off >>= 1) m = fmaxf(m, __shfl_down(m, off));
        m = __shfl(m, 0);
        float psum = 0.f;
        for (int e = start + lane; e < end; e += 64) {
            float sc = ss[esrc[e]] + sd;
            sc = sc > 0.f ? sc : ALPHA * sc;
            float p = __expf(sc - m);
            psum += p;
            att[e] = p;
        }
#pragma unroll
        for (int off = 32; off; off >>= 1) psum += __shfl_down(psum, off);
        psum = __shfl(psum, 0);
        float inv = 1.f / (psum + GAT_EPS);
        for (int e = start + lane; e < end; e += 64) att[e] *= inv;
    }
}

// ---------------- aggregate Fout=256 layers, XCD-tiled ----------------
// grid: N*8 blocks, 64 threads. block id = n*8 + tile; tile -> (head = tile>>1,
// 128-feature half = tile&1). With round-robin block->XCD dispatch, tile t pins
// to XCD t, so each XCD's gather working set is one 5 MB column slice (~L2-resident).
__global__ __launch_bounds__(64) void agg256_kernel(const _Float16* __restrict__ WH16,
                                                    const int* __restrict__ rowptr,
                                                    const int* __restrict__ esrc,
                                                    const float* __restrict__ ATT,
                                                    _Float16* __restrict__ X16,
                                                    int use_skip, int N) {
    int id = blockIdx.x;
    int tile = id & 7;
    int n = id >> 3;
    int h = tile >> 1;
    int lane = threadIdx.x;
    int base = h * 256 + (tile & 1) * 128 + lane * 2;
    int start = rowptr[n], end = rowptr[n + 1];
    const float* ap = ATT + (size_t)h * N_EDGES;
    float a0 = 0.f, a1 = 0.f;
    int e = start;
    for (; e + 4 <= end; e += 4) {
        int s0 = esrc[e], s1 = esrc[e + 1], s2 = esrc[e + 2], s3 = esrc[e + 3];
        float p0 = ap[e], p1 = ap[e + 1], p2 = ap[e + 2], p3 = ap[e + 3];
        half2 w0 = *(const half2*)(WH16 + (size_t)s0 * 1024 + base);
        half2 w1 = *(const half2*)(WH16 + (size_t)s1 * 1024 + base);
        half2 w2 = *(const half2*)(WH16 + (size_t)s2 * 1024 + base);
        half2 w3 = *(const half2*)(WH16 + (size_t)s3 * 1024 + base);
        a0 += p0 * (float)w0.x + p1 * (float)w1.x + p2 * (float)w2.x + p3 * (float)w3.x;
        a1 += p0 * (float)w0.y + p1 * (float)w1.y + p2 * (float)w2.y + p3 * (float)w3.y;
    }
    for (; e < end; e++) {
        int s = esrc[e];
        float p = ap[e];
        half2 w = *(const half2*)(WH16 + (size_t)s * 1024 + base);
        a0 += p * (float)w.x; a1 += p * (float)w.y;
    }
    size_t o = (size_t)n * 1024 + base;
    float v0, v1;
    if (use_skip) {
        half2 sk = *(const half2*)(X16 + o);
        v0 = elu1(elu1(a0) + (float)sk.x);
        v1 = elu1(elu1(a1) + (float)sk.y);
    } else {
        v0 = elu1(elu1(a0));
        v1 = elu1(elu1(a1));
    }
    half2 r; r.x = (_Float16)v0; r.y = (_Float16)v1;
    *(half2*)(X16 + o) = r;
}

// ---------------- layer 3: all 6 heads fused, mean + sigmoid ----------------
__global__ __launch_bounds__(128) void agg726_kernel(const _Float16* __restrict__ WH16,
                                                     const int* __restrict__ rowptr,
                                                     const int* __restrict__ esrc,
                                                     const float* __restrict__ ATT,
                                                     float* __restrict__ out, int N) {
    __shared__ float part[2][128];
    int t = threadIdx.x, n = blockIdx.x;
    int lane = t & 63, wv = t >> 6;
    int h0 = wv * 3;
    int start = rowptr[n], end = rowptr[n + 1];
    float acc[3][2] = {};
    for (int e = start; e < end; e++) {
        int s = esrc[e];
        float p0 = ATT[(size_t)(h0 + 0) * N_EDGES + e];
        float p1 = ATT[(size_t)(h0 + 1) * N_EDGES + e];
        float p2 = ATT[(size_t)(h0 + 2) * N_EDGES + e];
        const _Float16* row = WH16 + (size_t)s * 768 + h0 * 121;
        acc[0][0] += p0 * (float)row[lane];
        acc[1][0] += p1 * (float)row[121 + lane];
        acc[2][0] += p2 * (float)row[242 + lane];
        if (lane < 57) {
            acc[0][1] += p0 * (float)row[64 + lane];
            acc[1][1] += p1 * (float)row[185 + lane];
            acc[2][1] += p2 * (float)row[306 + lane];
        }
    }
    float s0 = acc[0][0] + acc[1][0] + acc[2][0];
    float s1 = acc[0][1] + acc[1][1] + acc[2][1];
    part[wv][lane] = s0;
    if (lane < 57) part[wv][64 + lane] = s1;
    __syncthreads();
    if (t < 121) {
        float tot = (part[0][t] + part[1][t]) * (1.f / 6.f);
        out[(size_t)n * 121 + t] = 1.f / (1.f + __expf(-tot));
    }
}

extern "C" void kernel_launch(void* const* d_in, const int* in_sizes, int n_in,
                              void* d_out, int out_size, void* d_ws, size_t ws_size,
                              hipStream_t stream) {
    const float* x  = (const float*)d_in[0];
    const int*   ei = (const int*)d_in[1];
    const float* W1 = (const float*)d_in[2];
    const float* a1 = (const float*)d_in[3];
    const float* W2 = (const float*)d_in[4];
    const float* a2 = (const float*)d_in[5];
    const float* W3 = (const float*)d_in[6];
    const float* a3 = (const float*)d_in[7];
    float* out = (float*)d_out;
    const int N = N_NODES, E = N_EDGES;
    const int* src = ei;
    const int* dst = ei + E;

    char* ws = (char*)d_ws;
    size_t off = 0;
    auto alloc = [&](size_t b) { size_t o = off; off += (b + 255) & ~(size_t)255; return o; };
    _Float16* X16  = (_Float16*)(ws + alloc((size_t)MPAD * 1024 * 2)); // x1 then x2
    _Float16* WH16 = (_Float16*)(ws + alloc((size_t)MPAD * 1024 * 2)); // per-layer Wh
    _Float16* BT16 = (_Float16*)(ws + alloc((size_t)1024 * 1024 * 2)); // W^T fp16
    _Float16* A1   = (_Float16*)(ws + alloc((size_t)MPAD * 64 * 2));   // x fp16, K=64 pad
    _Float16* BT1  = (_Float16*)(ws + alloc((size_t)1024 * 64 * 2));   // W1^T fp16
    float* SS     = (float*)(ws + alloc((size_t)6 * N * 4));
    float* SD     = (float*)(ws + alloc((size_t)6 * N * 4));
    float* ATT    = (float*)(ws + alloc((size_t)6 * E * 4));
    int*   rowptr = (int*)(ws + alloc((size_t)(N + 1) * 4));
    int*   cursor = (int*)(ws + alloc((size_t)N * 4));
    int*   counts = (int*)(ws + alloc((size_t)N * 4));
    int*   esrc   = (int*)(ws + alloc((size_t)E * 4));

    // CSR by dst
    hipMemsetAsync(counts, 0, (size_t)N * 4, stream);
    hist_kernel<<<(E + 255) / 256, 256, 0, stream>>>(dst, counts, E);
    scan_kernel<<<1, 1024, 0, stream>>>(counts, rowptr, cursor, N);
    scatter_kernel<<<(E + 255) / 256, 256, 0, stream>>>(src, dst, cursor, esrc, E);
    // zero GEMM pad rows (rows 20000..20095) of X16
    hipMemsetAsync(X16 + (size_t)N * 1024, 0, (size_t)(MPAD - N) * 1024 * 2, stream);

    // ---- layer 1: 50 -> 4x256 concat (fp16 MFMA, K padded to 64) ----
    pack_x16<<<MPAD * 64 / 256, 256, 0, stream>>>(x, A1);
    pack_bt1<<<1024 * 64 / 256, 256, 0, stream>>>(W1, BT1);
    gemm_f16<<<dim3(8, 157), 256, 0, stream>>>(A1, BT1, WH16, N, 1024, 1024, 64);
    scores_kernel<<<N, 256, 0, stream>>>(WH16, a1, SS, SD, N, 4, 256, 1024);
    att_kernel<<<N, 64, 0, stream>>>(rowptr, esrc, SS, SD, ATT, N, 4);
    agg256_kernel<<<N * 8, 64, 0, stream>>>(WH16, rowptr, esrc, ATT, X16, 0, N);

    // ---- layer 2: 1024 -> 4x256 concat + skip (fp16 MFMA) ----
    pack_bt16<<<dim3(4, 1024), 256, 0, stream>>>(W2, BT16, 256, 1024);
    gemm_f16<<<dim3(8, 157), 256, 0, stream>>>(X16, BT16, WH16, N, 1024, 1024, 1024);
    scores_kernel<<<N, 256, 0, stream>>>(WH16, a2, SS, SD, N, 4, 256, 1024);
    att_kernel<<<N, 64, 0, stream>>>(rowptr, esrc, SS, SD, ATT, N, 4);
    agg256_kernel<<<N * 8, 64, 0, stream>>>(WH16, rowptr, esrc, ATT, X16, 1, N);

    // ---- layer 3: 1024 -> 6x121, mean over heads, sigmoid ----
    pack_bt16<<<dim3(4, 768), 256, 0, stream>>>(W3, BT16, 121, 726);
    gemm_f16<<<dim3(6, 157), 256, 0, stream>>>(X16, BT16, WH16, N, 726, 768, 1024);
    scores_kernel<<<N, 384, 0, stream>>>(WH16, a3, SS, SD, N, 6, 121, 768);
    att_kernel<<<N, 64, 0, stream>>>(rowptr, esrc, SS, SD, ATT, N, 6);
    agg726_kernel<<<N, 128, 0, stream>>>(WH16, rowptr, esrc, ATT, out, N);
}

// Round 5
// 664.133 us; speedup vs baseline: 3.0910x; 1.0354x over previous
//
#include <hip/hip_runtime.h>
#include <cstdint>

#define N_NODES 20000
#define N_EDGES 320000
#define ALPHA 0.2f
#define GAT_EPS 1e-16f
#define MPAD 20096           // 157 * 128
#define SCAN_BLKS 80

typedef __attribute__((ext_vector_type(8))) _Float16 half8;
typedef __attribute__((ext_vector_type(4))) _Float16 half4;
typedef __attribute__((ext_vector_type(2))) _Float16 half2;
typedef __attribute__((ext_vector_type(4))) float f32x4;

__device__ __forceinline__ float elu1(float x) { return x > 0.f ? x : __expf(x) - 1.f; }

__device__ __forceinline__ void async16(const void* g, void* l) {
    __builtin_amdgcn_global_load_lds(
        (const __attribute__((address_space(1))) unsigned int*)g,
        (__attribute__((address_space(3))) unsigned int*)l, 16, 0, 0);
}

// ---------------- CSR build ----------------
__global__ void hist_kernel(const int* __restrict__ dst, int* __restrict__ counts, int E) {
    int e = blockIdx.x * blockDim.x + threadIdx.x;
    if (e < E) atomicAdd(&counts[dst[e]], 1);
}

// multi-block exclusive scan of counts -> rowptr/cursor
__global__ void scan1_kernel(const int* __restrict__ counts, int* __restrict__ excl,
                             int* __restrict__ partial, int N) {
    __shared__ int sh[256];
    int t = threadIdx.x, b = blockIdx.x;
    int i = b * 256 + t;
    int v = (i < N) ? counts[i] : 0;
    sh[t] = v;
    __syncthreads();
    for (int d = 1; d < 256; d <<= 1) {
        int x = (t >= d) ? sh[t - d] : 0;
        __syncthreads();
        sh[t] += x;
        __syncthreads();
    }
    if (i < N) excl[i] = sh[t] - v;
    if (t == 255) partial[b] = sh[255];
}

__global__ void scan2_kernel(int* __restrict__ partial) {
    __shared__ int sh[128];
    int t = threadIdx.x;
    int v = (t < SCAN_BLKS) ? partial[t] : 0;
    sh[t] = v;
    __syncthreads();
    for (int d = 1; d < 128; d <<= 1) {
        int x = (t >= d) ? sh[t - d] : 0;
        __syncthreads();
        sh[t] += x;
        __syncthreads();
    }
    if (t < SCAN_BLKS) partial[t] = sh[t] - v;
}

__global__ void scan3_kernel(const int* __restrict__ excl, const int* __restrict__ partial,
                             int* __restrict__ rowptr, int* __restrict__ cursor, int N, int E) {
    int t = threadIdx.x, b = blockIdx.x;
    int i = b * 256 + t;
    if (i < N) {
        int v = excl[i] + partial[b];
        rowptr[i] = v;
        cursor[i] = v;
    }
    if (i == 0) rowptr[N] = E;
}

__global__ void scatter_kernel(const int* __restrict__ src, const int* __restrict__ dst,
                               int* __restrict__ cursor, int* __restrict__ esrc, int E) {
    int e = blockIdx.x * blockDim.x + threadIdx.x;
    if (e < E) {
        int p = atomicAdd(&cursor[dst[e]], 1);
        esrc[p] = src[e];
    }
}

// ---------------- pack x (fp32, 20000x50) -> A1 fp16 [MPAD][64], K zero-padded ----------------
__global__ void pack_x16(const float* __restrict__ x, _Float16* __restrict__ A) {
    int idx = blockIdx.x * 256 + threadIdx.x;   // MPAD*64
    int r = idx >> 6, c = idx & 63;
    float v = (r < N_NODES && c < 50) ? x[r * 50 + c] : 0.f;
    A[idx] = (_Float16)v;
}

// ---------------- pack W1 (4,50,256) -> BT1 fp16 [1024][64] ----------------
__global__ void pack_bt1(const float* __restrict__ W, _Float16* __restrict__ Bt) {
    int idx = blockIdx.x * 256 + threadIdx.x;   // 1024*64
    int c = idx >> 6, k = idx & 63;
    int h = c >> 8, f = c & 255;
    float v = (k < 50) ? W[((size_t)h * 50 + k) * 256 + f] : 0.f;
    Bt[idx] = (_Float16)v;
}

// ---------------- pack W (fp32, K=1024) -> BT fp16 [Cpad][1024] ----------------
__global__ void pack_bt16(const float* __restrict__ W, _Float16* __restrict__ Bt,
                          int F, int Ctot) {
    int c = blockIdx.y;
    int k = blockIdx.x * blockDim.x + threadIdx.x;
    float v = 0.f;
    if (c < Ctot) {
        int h = c / F, f = c - h * F;
        v = W[(size_t)h * 1024 * F + (size_t)k * F + f];
    }
    Bt[(size_t)c * 1024 + k] = (_Float16)v;
}

// ---------------- fp16 MFMA GEMM, BK=64, XOR-swizzled LDS ----------------
// C[M][Ntot](fp16, ld) = A[MPAD][Kdim] @ BT^T.  Kdim % 64 == 0.
// LDS tile: 128 rows x 64 halves; 16-B group g of row R stored at g^(R&7).
// Staging permutes the per-lane GLOBAL address (LDS dest must stay lane-linear).
__global__ __launch_bounds__(256) void gemm_f16(const _Float16* __restrict__ A,
                                                const _Float16* __restrict__ BT,
                                                _Float16* __restrict__ C,
                                                int M, int Ntot, int ld, int Kdim) {
    __shared__ __align__(16) _Float16 sA[128 * 64];
    __shared__ __align__(16) _Float16 sB[128 * 64];
    int t = threadIdx.x;
    int row0 = blockIdx.y * 128, col0 = blockIdx.x * 128;
    int lane = t & 63, wave = t >> 6;
    int wm = wave >> 1, wn = wave & 1;
    int fr = lane & 15;
    int fq = lane >> 4;        // 0..3

    const _Float16* gA = A + (size_t)row0 * Kdim;
    const _Float16* gB = BT + (size_t)col0 * Kdim;

    int sR[4], sgl[4];
#pragma unroll
    for (int i = 0; i < 4; i++) {
        int m = i * 256 + t;
        sR[i] = m >> 3;
        sgl[i] = (m & 7) ^ (sR[i] & 7);
    }

    f32x4 acc[4][4] = {};

    for (int k0 = 0; k0 < Kdim; k0 += 64) {
        __syncthreads();
#pragma unroll
        for (int i = 0; i < 4; i++) {
            const _Float16* pa = gA + (size_t)sR[i] * Kdim + k0 + sgl[i] * 8;
            const _Float16* pb = gB + (size_t)sR[i] * Kdim + k0 + sgl[i] * 8;
            async16(pa, sA + (i * 256 + t) * 8);
            async16(pb, sB + (i * 256 + t) * 8);
        }
        __syncthreads();
#pragma unroll
        for (int ks = 0; ks < 2; ks++) {
            half8 af[4], bf[4];
#pragma unroll
            for (int mt = 0; mt < 4; mt++) {
                int R = wm * 64 + mt * 16 + fr;
                int gp = (ks * 4 + fq) ^ (R & 7);
                af[mt] = *(const half8*)(sA + R * 64 + gp * 8);
            }
#pragma unroll
            for (int nt = 0; nt < 4; nt++) {
                int R = wn * 64 + nt * 16 + fr;
                int gp = (ks * 4 + fq) ^ (R & 7);
                bf[nt] = *(const half8*)(sB + R * 64 + gp * 8);
            }
#pragma unroll
            for (int mt = 0; mt < 4; mt++)
#pragma unroll
                for (int nt = 0; nt < 4; nt++)
                    acc[mt][nt] = __builtin_amdgcn_mfma_f32_16x16x32_f16(af[mt], bf[nt], acc[mt][nt], 0, 0, 0);
        }
    }

    int rbase = row0 + wm * 64 + ((lane >> 4) << 2);
    int cbase = col0 + wn * 64 + (lane & 15);
#pragma unroll
    for (int mt = 0; mt < 4; mt++)
#pragma unroll
        for (int nt = 0; nt < 4; nt++) {
            int gc = cbase + nt * 16;
            if (gc >= Ntot) continue;
#pragma unroll
            for (int r = 0; r < 4; r++) {
                int gr = rbase + mt * 16 + r;
                if (gr < M) C[(size_t)gr * ld + gc] = (_Float16)acc[mt][nt][r];
            }
        }
}

// ---------------- attention scores (fp16 Wh) ----------------
__global__ void scores_kernel(const _Float16* __restrict__ Wh, const float* __restrict__ a,
                              float* __restrict__ ssrc, float* __restrict__ sdst,
                              int N, int H, int Fout, int ld) {
    int n = blockIdx.x;
    int h = threadIdx.x >> 6;
    int lane = threadIdx.x & 63;
    if (h >= H) return;
    const _Float16* row = Wh + (size_t)n * ld + h * Fout;
    const float* ah = a + (size_t)h * 2 * Fout;
    float s0 = 0.f, s1 = 0.f;
    for (int f = lane; f < Fout; f += 64) {
        float w = (float)row[f];
        s0 += w * ah[f];
        s1 += w * ah[Fout + f];
    }
#pragma unroll
    for (int off = 32; off; off >>= 1) {
        s0 += __shfl_down(s0, off);
        s1 += __shfl_down(s1, off);
    }
    if (lane == 0) {
        ssrc[(size_t)h * N + n] = s0;
        sdst[(size_t)h * N + n] = s1;
    }
}

// ---------------- per-edge attention weights (CSR order) ----------------
__global__ __launch_bounds__(64) void att_kernel(const int* __restrict__ rowptr,
                                                 const int* __restrict__ esrc,
                                                 const float* __restrict__ SS,
                                                 const float* __restrict__ SD,
                                                 float* __restrict__ ATT, int N, int H) {
    int n = blockIdx.x, lane = threadIdx.x;
    int start = rowptr[n], end = rowptr[n + 1];
    for (int h = 0; h < H; h++) {
        const float* ss = SS + (size_t)h * N;
        float sd = SD[(size_t)h * N + n];
        float* att = ATT + (size_t)h * N_EDGES;
        float m = -INFINITY;
        for (int e = start + lane; e < end; e += 64) {
            float sc = ss[esrc[e]] + sd;
            sc = sc > 0.f ? sc : ALPHA * sc;
            m = fmaxf(m, sc);
        }
#pragma unroll
        for (int off = 32; off; off >>= 1) m = fmaxf(m, __shfl_down(m, off));
        m = __shfl(m, 0);
        float psum = 0.f;
        for (int e = start + lane; e < end; e += 64) {
            float sc = ss[esrc[e]] + sd;
            sc = sc > 0.f ? sc : ALPHA * sc;
            float p = __expf(sc - m);
            psum += p;
            att[e] = p;
        }
#pragma unroll
        for (int off = 32; off; off >>= 1) psum += __shfl_down(psum, off);
        psum = __shfl(psum, 0);
        float inv = 1.f / (psum + GAT_EPS);
        for (int e = start + lane; e < end; e += 64) att[e] *= inv;
    }
}

// ---------------- aggregate Fout=256 layers, XCD-tiled ----------------
__global__ __launch_bounds__(64) void agg256_kernel(const _Float16* __restrict__ WH16,
                                                    const int* __restrict__ rowptr,
                                                    const int* __restrict__ esrc,
                                                    const float* __restrict__ ATT,
                                                    _Float16* __restrict__ X16,
                                                    int use_skip, int N) {
    int id = blockIdx.x;
    int tile = id & 7;
    int n = id >> 3;
    int h = tile >> 1;
    int lane = threadIdx.x;
    int base = h * 256 + (tile & 1) * 128 + lane * 2;
    int start = rowptr[n], end = rowptr[n + 1];
    const float* ap = ATT + (size_t)h * N_EDGES;
    float a0 = 0.f, a1 = 0.f;
    int e = start;
    for (; e + 4 <= end; e += 4) {
        int s0 = esrc[e], s1 = esrc[e + 1], s2 = esrc[e + 2], s3 = esrc[e + 3];
        float p0 = ap[e], p1 = ap[e + 1], p2 = ap[e + 2], p3 = ap[e + 3];
        half2 w0 = *(const half2*)(WH16 + (size_t)s0 * 1024 + base);
        half2 w1 = *(const half2*)(WH16 + (size_t)s1 * 1024 + base);
        half2 w2 = *(const half2*)(WH16 + (size_t)s2 * 1024 + base);
        half2 w3 = *(const half2*)(WH16 + (size_t)s3 * 1024 + base);
        a0 += p0 * (float)w0.x + p1 * (float)w1.x + p2 * (float)w2.x + p3 * (float)w3.x;
        a1 += p0 * (float)w0.y + p1 * (float)w1.y + p2 * (float)w2.y + p3 * (float)w3.y;
    }
    for (; e < end; e++) {
        int s = esrc[e];
        float p = ap[e];
        half2 w = *(const half2*)(WH16 + (size_t)s * 1024 + base);
        a0 += p * (float)w.x; a1 += p * (float)w.y;
    }
    size_t o = (size_t)n * 1024 + base;
    float v0, v1;
    if (use_skip) {
        half2 sk = *(const half2*)(X16 + o);
        v0 = elu1(elu1(a0) + (float)sk.x);
        v1 = elu1(elu1(a1) + (float)sk.y);
    } else {
        v0 = elu1(elu1(a0));
        v1 = elu1(elu1(a1));
    }
    half2 r; r.x = (_Float16)v0; r.y = (_Float16)v1;
    *(half2*)(X16 + o) = r;
}

// ---------------- layer 3: all 6 heads fused, mean + sigmoid ----------------
__global__ __launch_bounds__(128) void agg726_kernel(const _Float16* __restrict__ WH16,
                                                     const int* __restrict__ rowptr,
                                                     const int* __restrict__ esrc,
                                                     const float* __restrict__ ATT,
                                                     float* __restrict__ out, int N) {
    __shared__ float part[2][128];
    int t = threadIdx.x, n = blockIdx.x;
    int lane = t & 63, wv = t >> 6;
    int h0 = wv * 3;
    int start = rowptr[n], end = rowptr[n + 1];
    float acc[3][2] = {};
    for (int e = start; e < end; e++) {
        int s = esrc[e];
        float p0 = ATT[(size_t)(h0 + 0) * N_EDGES + e];
        float p1 = ATT[(size_t)(h0 + 1) * N_EDGES + e];
        float p2 = ATT[(size_t)(h0 + 2) * N_EDGES + e];
        const _Float16* row = WH16 + (size_t)s * 768 + h0 * 121;
        acc[0][0] += p0 * (float)row[lane];
        acc[1][0] += p1 * (float)row[121 + lane];
        acc[2][0] += p2 * (float)row[242 + lane];
        if (lane < 57) {
            acc[0][1] += p0 * (float)row[64 + lane];
            acc[1][1] += p1 * (float)row[185 + lane];
            acc[2][1] += p2 * (float)row[306 + lane];
        }
    }
    float s0 = acc[0][0] + acc[1][0] + acc[2][0];
    float s1 = acc[0][1] + acc[1][1] + acc[2][1];
    part[wv][lane] = s0;
    if (lane < 57) part[wv][64 + lane] = s1;
    __syncthreads();
    if (t < 121) {
        float tot = (part[0][t] + part[1][t]) * (1.f / 6.f);
        out[(size_t)n * 121 + t] = 1.f / (1.f + __expf(-tot));
    }
}

extern "C" void kernel_launch(void* const* d_in, const int* in_sizes, int n_in,
                              void* d_out, int out_size, void* d_ws, size_t ws_size,
                              hipStream_t stream) {
    const float* x  = (const float*)d_in[0];
    const int*   ei = (const int*)d_in[1];
    const float* W1 = (const float*)d_in[2];
    const float* a1 = (const float*)d_in[3];
    const float* W2 = (const float*)d_in[4];
    const float* a2 = (const float*)d_in[5];
    const float* W3 = (const float*)d_in[6];
    const float* a3 = (const float*)d_in[7];
    float* out = (float*)d_out;
    const int N = N_NODES, E = N_EDGES;
    const int* src = ei;
    const int* dst = ei + E;

    char* ws = (char*)d_ws;
    size_t off = 0;
    auto alloc = [&](size_t b) { size_t o = off; off += (b + 255) & ~(size_t)255; return o; };
    _Float16* X16  = (_Float16*)(ws + alloc((size_t)MPAD * 1024 * 2)); // x1 then x2
    _Float16* WH16 = (_Float16*)(ws + alloc((size_t)MPAD * 1024 * 2)); // per-layer Wh
    _Float16* BT16 = (_Float16*)(ws + alloc((size_t)1024 * 1024 * 2)); // W^T fp16
    _Float16* A1   = (_Float16*)(ws + alloc((size_t)MPAD * 64 * 2));   // x fp16, K=64 pad
    _Float16* BT1  = (_Float16*)(ws + alloc((size_t)1024 * 64 * 2));   // W1^T fp16
    float* SS     = (float*)(ws + alloc((size_t)6 * N * 4));
    float* SD     = (float*)(ws + alloc((size_t)6 * N * 4));
    float* ATT    = (float*)(ws + alloc((size_t)6 * E * 4));
    int*   rowptr = (int*)(ws + alloc((size_t)(N + 1) * 4));
    int*   cursor = (int*)(ws + alloc((size_t)N * 4));
    int*   counts = (int*)(ws + alloc((size_t)N * 4));
    int*   excl   = (int*)(ws + alloc((size_t)N * 4));
    int*   partial= (int*)(ws + alloc((size_t)SCAN_BLKS * 4));
    int*   esrc   = (int*)(ws + alloc((size_t)E * 4));

    // CSR by dst (multi-block scan)
    hipMemsetAsync(counts, 0, (size_t)N * 4, stream);
    hist_kernel<<<(E + 255) / 256, 256, 0, stream>>>(dst, counts, E);
    scan1_kernel<<<SCAN_BLKS, 256, 0, stream>>>(counts, excl, partial, N);
    scan2_kernel<<<1, 128, 0, stream>>>(partial);
    scan3_kernel<<<SCAN_BLKS, 256, 0, stream>>>(excl, partial, rowptr, cursor, N, E);
    scatter_kernel<<<(E + 255) / 256, 256, 0, stream>>>(src, dst, cursor, esrc, E);
    // zero GEMM pad rows (rows 20000..20095) of X16
    hipMemsetAsync(X16 + (size_t)N * 1024, 0, (size_t)(MPAD - N) * 1024 * 2, stream);

    // ---- layer 1: 50 -> 4x256 concat (fp16 MFMA, K padded to 64) ----
    pack_x16<<<MPAD * 64 / 256, 256, 0, stream>>>(x, A1);
    pack_bt1<<<1024 * 64 / 256, 256, 0, stream>>>(W1, BT1);
    gemm_f16<<<dim3(8, 157), 256, 0, stream>>>(A1, BT1, WH16, N, 1024, 1024, 64);
    scores_kernel<<<N, 256, 0, stream>>>(WH16, a1, SS, SD, N, 4, 256, 1024);
    att_kernel<<<N, 64, 0, stream>>>(rowptr, esrc, SS, SD, ATT, N, 4);
    agg256_kernel<<<N * 8, 64, 0, stream>>>(WH16, rowptr, esrc, ATT, X16, 0, N);

    // ---- layer 2: 1024 -> 4x256 concat + skip (fp16 MFMA) ----
    pack_bt16<<<dim3(4, 1024), 256, 0, stream>>>(W2, BT16, 256, 1024);
    gemm_f16<<<dim3(8, 157), 256, 0, stream>>>(X16, BT16, WH16, N, 1024, 1024, 1024);
    scores_kernel<<<N, 256, 0, stream>>>(WH16, a2, SS, SD, N, 4, 256, 1024);
    att_kernel<<<N, 64, 0, stream>>>(rowptr, esrc, SS, SD, ATT, N, 4);
    agg256_kernel<<<N * 8, 64, 0, stream>>>(WH16, rowptr, esrc, ATT, X16, 1, N);

    // ---- layer 3: 1024 -> 6x121, mean over heads, sigmoid ----
    pack_bt16<<<dim3(4, 768), 256, 0, stream>>>(W3, BT16, 121, 726);
    gemm_f16<<<dim3(6, 157), 256, 0, stream>>>(X16, BT16, WH16, N, 726, 768, 1024);
    scores_kernel<<<N, 384, 0, stream>>>(WH16, a3, SS, SD, N, 6, 121, 768);
    att_kernel<<<N, 64, 0, stream>>>(rowptr, esrc, SS, SD, ATT, N, 6);
    agg726_kernel<<<N, 128, 0, stream>>>(WH16, rowptr, esrc, ATT, out, N);
}